// Round 9
// baseline (169.618 us; speedup 1.0000x reference)
//
#include <hip/hip_runtime.h>
#include <math.h>

// Problem constants (reference: B=4, S=512, E=512, H=8, DH=64, HID=128)
#define BATCH 4
#define SEQ   512
#define EMB   512
#define NH    8
#define DHD   64
#define HIDN  128
#define ALPHA 0.1f
#define EPSS  0.05f

// LUT for the pointwise conv-chain -> sigmoid function of `scaled`
#define LUTN  2048
#define XMIN  (-0.4f)
#define XSTEP (0.8f / LUTN)

typedef __attribute__((ext_vector_type(8))) short  bf16x8;
typedef __attribute__((ext_vector_type(4))) float  f32x4;
#define MFMA(a,b,c) __builtin_amdgcn_mfma_f32_16x16x32_bf16((a),(b),(c),0,0,0)

__device__ __forceinline__ unsigned short f2bf(float f) {
    union { float f; unsigned u; } v; v.f = f;
    unsigned r = v.u + 0x7fffu + ((v.u >> 16) & 1u);   // RNE; inputs finite
    return (unsigned short)(r >> 16);
}
__device__ __forceinline__ float bf2f(unsigned short h) {
    union { unsigned u; float f; } v; v.u = ((unsigned)h) << 16;
    return v.f;
}
__device__ __forceinline__ float f16tof(unsigned short h) {
    union { unsigned short s; _Float16 f; } v; v.s = h; return (float)v.f;
}
__device__ __forceinline__ unsigned short ftof16(float f) {
    union { unsigned short s; _Float16 f; } v; v.f = (_Float16)f; return v.s;
}

// async global->LDS, 16B per lane; LDS dst = uniform base + lane*16
__device__ __forceinline__ void async_lds16(const unsigned short* g, unsigned short* l) {
    __builtin_amdgcn_global_load_lds(
        (const __attribute__((address_space(1))) void*)g,
        (__attribute__((address_space(3))) void*)l, 16, 0, 0);
}

// ---------------- BK=64 GEMM core (64/32-row blocks) ---------------------
template<int KS, int UN, int MT>
__device__ __forceinline__ void gemm_core64(
    const unsigned short* __restrict__ A, const unsigned short* __restrict__ B,
    int m0, int n0, unsigned short* sA, unsigned short* sB, f32x4 (&acc)[2][4])
{
    const int K = KS * 64;
    const int tid = threadIdx.x, w = tid >> 6, lane = tid & 63;
    const int quad = lane >> 4, r = lane & 15;
    const int wm = w >> 1, wn = w & 1;
    const int lrow = lane >> 3, lc = lane & 7;
    const int sc = lc ^ lrow;                     // swizzled global chunk
    constexpr int AF = MT / 32;                   // A frags per wave
    constexpr int NB = UN;                        // B staging calls per wave

    const unsigned short* ag[2]; unsigned short* dAu[2];
    #pragma unroll
    for (int c = 0; c < AF; c++) {
        const int rb = w * (8 * AF) + c * 8;
        ag[c]  = A + (long)(m0 + rb + lrow) * K + sc * 8;
        dAu[c] = sA + rb * 64;
    }
    const unsigned short* bg[4]; unsigned short* dBu[4];
    #pragma unroll
    for (int c = 0; c < NB; c++) {
        const int rb = w * (8 * NB) + c * 8;
        bg[c]  = B + (long)(n0 + rb + lrow) * K + sc * 8;
        dBu[c] = sB + rb * 64;
    }

    for (int s = 0; s < KS; s++) {
        const int k0 = s * 64;
        #pragma unroll
        for (int c = 0; c < AF; c++) async_lds16(ag[c] + k0, dAu[c]);
        #pragma unroll
        for (int c = 0; c < NB; c++) async_lds16(bg[c] + k0, dBu[c]);
        __syncthreads();
        #pragma unroll
        for (int kc = 0; kc < 2; kc++) {
            bf16x8 af[2], bfr[4];
            #pragma unroll
            for (int t = 0; t < AF; t++) {
                const int row = wm * (16 * AF) + t * 16 + r;
                af[t] = *(const bf16x8*)(sA + row * 64 + ((kc * 4 + quad) ^ (row & 7)) * 8);
            }
            #pragma unroll
            for (int u = 0; u < UN; u++) {
                const int row = wn * (16 * UN) + u * 16 + r;
                bfr[u] = *(const bf16x8*)(sB + row * 64 + ((kc * 4 + quad) ^ (row & 7)) * 8);
            }
            #pragma unroll
            for (int t = 0; t < AF; t++)
                #pragma unroll
                for (int u = 0; u < UN; u++)
                    acc[t][u] = MFMA(af[t], bfr[u], acc[t][u]);
        }
        __syncthreads();
    }
}

// ---------------- fused QKV projection: 128x128 tiles --------------------
// A = x_ext [2048,1536]=[xh|xl|xh]; B = w_ext [1536,1536]=[wh|wh|wl].
// 32 MFMAs/wave per barrier pair (m93->m97 ladder step). Grid (12,16).
__global__ __launch_bounds__(256) void gemm_qkv(
    const unsigned short* __restrict__ x_ext, const unsigned short* __restrict__ w_ext,
    const float* __restrict__ bq, const float* __restrict__ bk, const float* __restrict__ bv,
    unsigned short* __restrict__ q_ext, unsigned short* __restrict__ k_ext,
    unsigned short* __restrict__ vT)
{
    __shared__ __align__(16) unsigned short sA[128 * 64];
    __shared__ __align__(16) unsigned short sB[128 * 64];
    __shared__ float sC[64 * 132];

    const int m0 = blockIdx.y * 128, n0 = blockIdx.x * 128;
    const int tid = threadIdx.x, w = tid >> 6, lane = tid & 63;
    const int quad = lane >> 4, r = lane & 15;
    const int wm = w >> 1, wn = w & 1;
    const int lrow = lane >> 3, lc = lane & 7;
    const int sc = lc ^ lrow;

    f32x4 acc[4][4] = {};
    const unsigned short* ag[4]; const unsigned short* bg[4];
    unsigned short *dA[4], *dB[4];
    #pragma unroll
    for (int c = 0; c < 4; c++) {
        const int rb = w * 32 + c * 8;
        ag[c] = x_ext + (long)(m0 + rb + lrow) * 1536 + sc * 8;
        bg[c] = w_ext + (long)(n0 + rb + lrow) * 1536 + sc * 8;
        dA[c] = sA + rb * 64;
        dB[c] = sB + rb * 64;
    }

    for (int s = 0; s < 24; s++) {
        const int k0 = s * 64;
        #pragma unroll
        for (int c = 0; c < 4; c++) { async_lds16(ag[c] + k0, dA[c]); async_lds16(bg[c] + k0, dB[c]); }
        __syncthreads();
        #pragma unroll
        for (int kc = 0; kc < 2; kc++) {
            bf16x8 af[4], bfr[4];
            #pragma unroll
            for (int t = 0; t < 4; t++) {
                const int row = wm * 64 + t * 16 + r;
                af[t] = *(const bf16x8*)(sA + row * 64 + ((kc * 4 + quad) ^ (row & 7)) * 8);
            }
            #pragma unroll
            for (int u = 0; u < 4; u++) {
                const int row = wn * 64 + u * 16 + r;
                bfr[u] = *(const bf16x8*)(sB + row * 64 + ((kc * 4 + quad) ^ (row & 7)) * 8);
            }
            #pragma unroll
            for (int t = 0; t < 4; t++)
                #pragma unroll
                for (int u = 0; u < 4; u++)
                    acc[t][u] = MFMA(af[t], bfr[u], acc[t][u]);
        }
        __syncthreads();
    }

    // epilogue: two 64-row passes through a 64x132 fp32 LDS tile
    const int which = n0 >> 9;       // 0:q 1:k 2:v
    const int n0l = n0 & 511;
    const int b = m0 >> 9;

    #pragma unroll
    for (int p = 0; p < 2; p++) {
        if (wm == p) {
            #pragma unroll
            for (int t = 0; t < 4; t++)
                #pragma unroll
                for (int u = 0; u < 4; u++)
                    #pragma unroll
                    for (int g = 0; g < 4; g++)
                        sC[(t * 16 + quad * 4 + g) * 132 + wn * 64 + u * 16 + r] = acc[t][u][g];
        }
        __syncthreads();
        const int s0r = (m0 & 511) + p * 64;
        if (which < 2) {
            const float scl = (which == 0) ? 0.125f : 1.0f;
            const float* bias = (which == 0) ? bq : bk;
            unsigned* dst = (unsigned*)((which == 0) ? q_ext : k_ext);
            #pragma unroll
            for (int seg = 0; seg < 3; seg++) {
                const bool lo = (which == 0) ? (seg == 1) : (seg == 2);
                #pragma unroll
                for (int it = 0; it < 16; it++) {
                    const int idx = it * 256 + tid;        // 0..4095
                    const int sl = idx >> 6;               // 0..63
                    const int jc = idx & 63;               // col pair
                    const int nc = jc * 2;
                    const int n2 = n0l + nc;
                    const int h = n2 >> 6, d = n2 & 63;
                    float v0 = (sC[sl * 132 + nc]     + bias[n2])     * scl;
                    float v1 = (sC[sl * 132 + nc + 1] + bias[n2 + 1]) * scl;
                    unsigned short a0 = f2bf(v0), a1 = f2bf(v1);
                    if (lo) { a0 = f2bf(v0 - bf2f(a0)); a1 = f2bf(v1 - bf2f(a1)); }
                    const long orow = (long)(b * NH + h) * SEQ + s0r + sl;
                    dst[orow * 96 + seg * 32 + (d >> 1)] = (unsigned)a0 | ((unsigned)a1 << 16);
                }
            }
        } else {
            unsigned* dst = (unsigned*)vT;
            #pragma unroll
            for (int it = 0; it < 16; it++) {
                const int idx = it * 256 + tid;
                const int dcol = idx >> 5;                 // 0..127
                const int jc = idx & 31;                   // s pair
                const int sl = jc * 2;
                const int n2 = n0l + dcol;
                const int h = n2 >> 6, d = n2 & 63;
                const float bvv = bv[n2];
                const float v0 = sC[sl * 132 + dcol] + bvv;
                const float v1 = sC[(sl + 1) * 132 + dcol] + bvv;
                const long orow = (long)(b * NH + h) * DHD + d;
                dst[orow * 256 + ((m0 & 511) >> 1) + p * 32 + jc] =
                    (unsigned)f2bf(v0) | ((unsigned)f2bf(v1) << 16);
            }
        }
        __syncthreads();
    }
}

// ---------------- scores = q_ext @ k_ext^T per (b,h), K=192 -> fp16 ------
__global__ __launch_bounds__(256) void gemm_scores(
    const unsigned short* __restrict__ q_ext, const unsigned short* __restrict__ k_ext,
    unsigned short* __restrict__ scoresH)
{
    __shared__ __align__(16) unsigned short sA[64 * 64];
    __shared__ __align__(16) unsigned short sB[128 * 64];
    const int z = blockIdx.z;
    const int m0 = blockIdx.y * 64, n0 = blockIdx.x * 128;
    f32x4 acc[2][4] = {};
    gemm_core64<3, 4, 64>(q_ext + (long)z * SEQ * 192, k_ext + (long)z * SEQ * 192,
                          m0, n0, sA, sB, acc);

    const int tid = threadIdx.x, w = tid >> 6, lane = tid & 63;
    const int quad = lane >> 4, r = lane & 15;
    const int wm = w >> 1, wn = w & 1;
    unsigned short* hC = sB;   // reuse as 64x128 fp16 tile
    #pragma unroll
    for (int t = 0; t < 2; t++)
        #pragma unroll
        for (int u = 0; u < 4; u++)
            #pragma unroll
            for (int g = 0; g < 4; g++) {
                const int ml = wm * 32 + t * 16 + quad * 4 + g;
                const int nl = wn * 64 + u * 16 + r;
                hC[ml * 128 + nl] = ftof16(fminf(fmaxf(acc[t][u][g], -15.f), 15.f));
            }
    __syncthreads();
    #pragma unroll
    for (int it = 0; it < 4; it++) {
        const int id = it * 256 + tid;
        const int ml = id >> 4, ch = id & 15;
        *(uint4*)(scoresH + ((long)z * SEQ + m0 + ml) * SEQ + n0 + ch * 8) =
            *(const uint4*)(hC + ml * 128 + ch * 8);
    }
}

// ---------------- out = out_tmp @ wo^T + bo (32x64 tiles) ----------------
__global__ __launch_bounds__(256) void gemm_proj(
    const unsigned short* __restrict__ otmp, const unsigned short* __restrict__ woh,
    const float* __restrict__ bo, float* __restrict__ out)
{
    __shared__ __align__(16) unsigned short sA[32 * 64];
    __shared__ __align__(16) unsigned short sB[64 * 64];
    const int m0 = blockIdx.y * 32, n0 = blockIdx.x * 64;
    f32x4 acc[2][4] = {};
    gemm_core64<8, 2, 32>(otmp, woh, m0, n0, sA, sB, acc);
    const int tid = threadIdx.x, w = tid >> 6, lane = tid & 63;
    const int quad = lane >> 4, r = lane & 15;
    const int wm = w >> 1, wn = w & 1;
    #pragma unroll
    for (int u = 0; u < 2; u++)
        #pragma unroll
        for (int g = 0; g < 4; g++) {
            const int m = m0 + wm * 16 + quad * 4 + g;
            const int n = n0 + wn * 32 + u * 16 + r;
            out[(long)m * EMB + n] = acc[0][u][g] + bo[n];
        }
}

// ---------------- block reduction helpers (blockDim=256, 4 waves) --------
__device__ __forceinline__ float blockReduceSum(float v, float* sred) {
    #pragma unroll
    for (int o = 32; o > 0; o >>= 1) v += __shfl_down(v, o);
    __syncthreads();
    if ((threadIdx.x & 63) == 0) sred[threadIdx.x >> 6] = v;
    __syncthreads();
    return (sred[0] + sred[1]) + (sred[2] + sred[3]);
}
__device__ __forceinline__ float blockReduceMax(float v, float* sred) {
    #pragma unroll
    for (int o = 32; o > 0; o >>= 1) v = fmaxf(v, __shfl_down(v, o));
    __syncthreads();
    if ((threadIdx.x & 63) == 0) sred[threadIdx.x >> 6] = v;
    __syncthreads();
    return fmaxf(fmaxf(sred[0], sred[1]), fmaxf(sred[2], sred[3]));
}

// ---------------- fused prep: LUT + ext-K split builds -------------------
__global__ __launch_bounds__(256) void prep_kernel(
    const float* __restrict__ x,
    const float* __restrict__ wq, const float* __restrict__ wk,
    const float* __restrict__ wv, const float* __restrict__ wo,
    const float* __restrict__ w1, const float* __restrict__ b1,
    const float* __restrict__ w2, const float* __restrict__ b2,
    unsigned short* __restrict__ x_ext, unsigned short* __restrict__ w_ext,
    unsigned short* __restrict__ woh, float* __restrict__ lut)
{
    const int blk = blockIdx.x;
    if (blk < 9) {
        const int i = blk * 256 + threadIdx.x;
        if (i > LUTN) return;
        const float xv = XMIN + i * XSTEP;
        float a = 0.f;
        for (int h = 0; h < HIDN; h++) {
            float hv = xv * w1[h] + b1[h];
            hv = fminf(fmaxf(hv, -5.f), 5.f);
            hv = fmaxf(hv, 0.f);
            a += hv * w2[h];
        }
        a += b2[0];
        a = fminf(fmaxf(a, -5.f), 5.f);
        const float taylor = fminf(fmaxf(1.f + 2.5f * a, 0.5f), 1.5f);
        lut[i] = 1.f / (1.f + expf(-taylor));
        return;
    }
    const int i = (blk - 9) * 256 + threadIdx.x;  // 0 .. 2097151
    if (i < 1048576) {
        const int m = i >> 9, k = i & 511;
        const float v = x[i];
        const unsigned short h = f2bf(v), l = f2bf(v - bf2f(h));
        const long bb = (long)m * 1536 + k;
        x_ext[bb] = h; x_ext[bb + 512] = l; x_ext[bb + 1024] = h;   // [xh|xl|xh]
    } else if (i < 1835008) {
        const int j = i - 1048576;
        const int n = j >> 9, k = j & 511;
        const float v = (j < 262144) ? wq[j] : (j < 524288 ? wk[j - 262144] : wv[j - 524288]);
        const unsigned short h = f2bf(v), l = f2bf(v - bf2f(h));
        const long bb = (long)n * 1536 + k;
        w_ext[bb] = h; w_ext[bb + 512] = h; w_ext[bb + 1024] = l;   // [wh|wh|wl]
    } else {
        const int j = i - 1835008;
        woh[j] = f2bf(wo[j]);
    }
}

// ---------------- transform kernel: one block per (b,i) row --------------
__global__ __launch_bounds__(256) void transform_kernel(
    const unsigned short* __restrict__ scoresH, // [B,H,S,S] fp16 (clamped)
    const float* __restrict__ lut,              // [LUTN+1]
    unsigned short* __restrict__ t0H,           // [B,S,S] fp16
    float4* __restrict__ partials)              // [B*S] float4 slots
{
    const int rr = blockIdx.x;
    const int b = rr >> 9, i = rr & 511;
    const int tid = threadIdx.x;

    __shared__ float slut[LUTN + 1];
    __shared__ float sred[4];

    for (int u = tid; u <= LUTN; u += 256) slut[u] = lut[u];

    const unsigned* baseU =
        (const unsigned*)(scoresH + (((long)(b * NH)) * SEQ + i) * SEQ) + tid;
    float s0 = 0.f, s1 = 0.f;
    #pragma unroll
    for (int h = 0; h < NH; h++) {
        const unsigned pv = baseU[h * (SEQ * SEQ / 2)];
        s0 += f16tof((unsigned short)pv);
        s1 += f16tof((unsigned short)(pv >> 16));
    }
    float mv[2] = { s0 * 0.125f, s1 * 0.125f };
    __syncthreads();

    float sigv[2], mclip[2];
    float lmax = -1e30f;
    #pragma unroll
    for (int u = 0; u < 2; u++) {
        const float m = mv[u];
        const float x = fminf(fmaxf(m, -8.f), 8.f) * EPSS;
        float t = (x - XMIN) * (1.0f / XSTEP);
        int idx = (int)t;
        idx = idx < 0 ? 0 : (idx > LUTN - 1 ? LUTN - 1 : idx);
        const float frac = t - (float)idx;
        const float l0 = slut[idx], l1 = slut[idx + 1];
        sigv[u] = l0 + frac * (l1 - l0);
        const float mc = fminf(fmaxf(m, -10.f), 10.f);
        mclip[u] = mc;
        lmax = fmaxf(lmax, mc);
    }

    const float rmax = blockReduceMax(lmax, sred);
    float ex[2], lsum = 0.f;
    #pragma unroll
    for (int u = 0; u < 2; u++) { ex[u] = expf(mclip[u] - rmax); lsum += ex[u]; }
    const float rsum = blockReduceSum(lsum, sred);
    const float inv = 1.f / rsum;

    float hent[2], lmax2 = -1e30f;
    #pragma unroll
    for (int u = 0; u < 2; u++) {
        const float p = ex[u] * inv;
        const float he = -p * logf(p + 1e-6f);
        hent[u] = 3.f * he;
        lmax2 = fmaxf(lmax2, hent[u]);
    }
    const float rmax2 = blockReduceMax(lmax2, sred);
    float ex2[2], lsum2 = 0.f;
    #pragma unroll
    for (int u = 0; u < 2; u++) { ex2[u] = expf(hent[u] - rmax2); lsum2 += ex2[u]; }
    const float rsum2 = blockReduceSum(lsum2, sred);
    const float inv2 = 1.f / rsum2;

    float tv[2];
    #pragma unroll
    for (int u = 0; u < 2; u++) tv[u] = sigv[u] * (ex2[u] * inv2);
    ((unsigned*)t0H)[((long)b * SEQ + i) * (SEQ / 2) + tid] =
        (unsigned)ftof16(tv[0]) | ((unsigned)ftof16(tv[1]) << 16);

    float s_m  = blockReduceSum(mv[0] + mv[1], sred);
    float s_m2 = blockReduceSum(mv[0] * mv[0] + mv[1] * mv[1], sred);
    float s_t  = blockReduceSum(tv[0] + tv[1], sred);
    float s_t2 = blockReduceSum(tv[0] * tv[0] + tv[1] * tv[1], sred);
    if (tid == 0) partials[rr] = make_float4(s_m, s_m2, s_t, s_t2);
}

// ---------------- fused coef + softmax + attn@v (64-row, 1-shot vT) ------
// Grid (8, 32). vT staging issued FIRST (overlaps with softmax compute);
// phase C has zero K-loop barriers.
__global__ __launch_bounds__(256) void softmax_attnv(
    const unsigned short* __restrict__ scoresH, // [B,H,S,S] fp16
    const unsigned short* __restrict__ t0H,     // [B,S,S] fp16
    const float4* __restrict__ partials,        // [B*S]
    const unsigned short* __restrict__ vT,      // [B,H,DH,S] bf16
    unsigned short* __restrict__ otmp)          // [B*S, E] bf16
{
    __shared__ __align__(16) unsigned short attnS[64 * 520];  // 66.6 KB
    __shared__ __align__(16) unsigned short vL[64 * 520];     // 66.6 KB
    __shared__ float sred[4];

    const int m0 = blockIdx.x * 64;
    const int z  = blockIdx.y;
    const int b  = z >> 3, h = z & 7;
    const int tid = threadIdx.x, wv = tid >> 6, lane = tid & 63;

    // 0) kick off full vT staging (64 rows x 1 KB), drains at first barrier
    const unsigned short* vg = vT + (long)z * DHD * SEQ + lane * 8;
    #pragma unroll
    for (int c = 0; c < 16; c++) {
        const int d = c * 4 + wv;
        async_lds16(vg + d * SEQ, vL + d * 520);
    }

    // --- phase A: coef (redundant per block) ---
    const float4 p0 = partials[b * SEQ + tid];
    const float4 p1 = partials[b * SEQ + tid + 256];
    float sm  = blockReduceSum(p0.x + p1.x, sred);
    float sm2 = blockReduceSum(p0.y + p1.y, sred);
    float st  = blockReduceSum(p0.z + p1.z, sred);
    float st2 = blockReduceSum(p0.w + p1.w, sred);
    const float n = (float)SEQ * (float)SEQ;
    const float gamma = fminf(fmaxf((sqrtf(sm2) + 1e-4f) / (sqrtf(st2) + 1e-4f), 0.8f), 1.2f);
    const float o_mean = sm / n, t0m = st / n;
    const float o_std = sqrtf(fmaxf(fmaxf(sm2 / n - o_mean * o_mean, 0.f), 0.01f));
    const float t_std = sqrtf(fmaxf(gamma * gamma * fmaxf(st2 / n - t0m * t0m, 0.f), 0.01f));
    const float gdyn = fminf(fmaxf(o_std / t_std, 0.8f), 1.2f);
    const float c1 = gdyn * gamma;
    const float c0 = o_mean - c1 * t0m;

    // --- phase B: softmax 64 rows -> LDS bf16 tile ---
    const int j0 = lane * 8;
    for (int it = 0; it < 16; it++) {
        const int rowl = it * 4 + wv;
        const bf16x8 sr = *(const bf16x8*)(scoresH + ((long)z * SEQ + m0 + rowl) * SEQ + j0);
        const bf16x8 tr = *(const bf16x8*)(t0H + ((long)b * SEQ + m0 + rowl) * SEQ + j0);
        float sv[8];
        float lmax = -1e30f;
        #pragma unroll
        for (int u = 0; u < 8; u++) {
            float s = f16tof((unsigned short)sr[u])
                    + ALPHA * (c0 + c1 * f16tof((unsigned short)tr[u]));
            s = fminf(fmaxf(s, -15.f), 15.f);
            sv[u] = s;
            lmax = fmaxf(lmax, s);
        }
        #pragma unroll
        for (int o = 32; o > 0; o >>= 1) lmax = fmaxf(lmax, __shfl_down(lmax, o));
        lmax = __shfl(lmax, 0);
        float lsum = 0.f;
        #pragma unroll
        for (int u = 0; u < 8; u++) { sv[u] = expf(sv[u] - lmax); lsum += sv[u]; }
        #pragma unroll
        for (int o = 32; o > 0; o >>= 1) lsum += __shfl_down(lsum, o);
        lsum = __shfl(lsum, 0);
        const float inv = 1.f / lsum;
        bf16x8 pk;
        #pragma unroll
        for (int u = 0; u < 8; u++) pk[u] = (short)f2bf(sv[u] * inv);
        *(bf16x8*)(attnS + rowl * 520 + j0) = pk;
    }
    __syncthreads();   // attnS visible + vT staging drained

    // --- phase C: attn(LDS) @ vL(LDS), no barriers in K loop ---
    const int quad = lane >> 4, r = lane & 15;
    f32x4 acc[4] = {};
    #pragma unroll
    for (int kc = 0; kc < 16; kc++) {
        const bf16x8 a = *(const bf16x8*)(attnS + (wv * 16 + r) * 520 + kc * 32 + quad * 8);
        #pragma unroll
        for (int u = 0; u < 4; u++) {
            const bf16x8 bb = *(const bf16x8*)(vL + (u * 16 + r) * 520 + kc * 32 + quad * 8);
            acc[u] = MFMA(a, bb, acc[u]);
        }
    }
    __syncthreads();

    // --- phase D: epilogue via fp32 LDS tile (overlay attnS) ---
    float* sC = (float*)attnS;   // 64 x 66
    #pragma unroll
    for (int u = 0; u < 4; u++)
        #pragma unroll
        for (int g = 0; g < 4; g++)
            sC[(wv * 16 + quad * 4 + g) * 66 + u * 16 + r] = acc[u][g];
    __syncthreads();
    unsigned* dst = (unsigned*)otmp;
    #pragma unroll
    for (int it = 0; it < 8; it++) {
        const int idx = it * 256 + tid;
        const int sr2 = idx >> 5, jc = idx & 31;
        const float v0 = sC[sr2 * 66 + jc * 2], v1 = sC[sr2 * 66 + jc * 2 + 1];
        dst[((long)(b * SEQ + m0 + sr2)) * 256 + h * 32 + jc] =
            (unsigned)f2bf(v0) | ((unsigned)f2bf(v1) << 16);
    }
}

// -------------------------------------------------------------------------
extern "C" void kernel_launch(void* const* d_in, const int* in_sizes, int n_in,
                              void* d_out, int out_size, void* d_ws, size_t ws_size,
                              hipStream_t stream) {
    const float* x  = (const float*)d_in[0];
    const float* wq = (const float*)d_in[1];
    const float* bq = (const float*)d_in[2];
    const float* wk = (const float*)d_in[3];
    const float* bk = (const float*)d_in[4];
    const float* wv = (const float*)d_in[5];
    const float* bv = (const float*)d_in[6];
    const float* wo = (const float*)d_in[7];
    const float* bo = (const float*)d_in[8];
    const float* w1 = (const float*)d_in[9];
    const float* b1 = (const float*)d_in[10];
    const float* w2 = (const float*)d_in[11];
    const float* b2 = (const float*)d_in[12];
    float* out = (float*)d_out;

    // ---- workspace layout (~48 MB) ----
    char* wsb = (char*)d_ws;
    unsigned short* scoresH = (unsigned short*)wsb;        // 16 MB [B,H,S,S] fp16
    unsigned short* t0H     = scoresH + 8388608;           // 2 MB  [B,S,S] fp16
    float4* partials = (float4*)(t0H + 1048576);           // 32 KB
    float*  lutbuf   = (float*)(partials + 2048);
    unsigned short* u16 = (unsigned short*)(wsb + (20u << 20));
    unsigned short* x_ext = u16;                           // 6 MB   [2048,1536]
    unsigned short* w_ext = x_ext + 3145728;               // 4.5 MB [1536,1536]
    unsigned short* q_ext = w_ext + 2359296;               // 6 MB   [B*H*S,192]
    unsigned short* k_ext = q_ext + 3145728;               // 6 MB
    unsigned short* vT    = k_ext + 3145728;               // 2 MB   [B,H,DH,S]
    unsigned short* otmp  = vT + 1048576;                  // 2 MB   [B*S, E]
    unsigned short* woh   = otmp + 1048576;                // 0.5 MB [E,E]

    // 1) prep: LUT + ext-K split builds
    prep_kernel<<<dim3(9 + 8192), dim3(256), 0, stream>>>(
        x, wq, wk, wv, wo, w1, b1, w2, b2, x_ext, w_ext, woh, lutbuf);

    // 2) fused QKV projection (compensated bf16, K=1536, 128x128 tiles)
    gemm_qkv<<<dim3(12, 16), dim3(256), 0, stream>>>(
        x_ext, w_ext, bq, bk, bv, q_ext, k_ext, vT);

    // 3) scores = q @ k^T per (b,h) (compensated, K=192) -> fp16, clamp
    gemm_scores<<<dim3(4, 8, 32), dim3(256), 0, stream>>>(q_ext, k_ext, scoresH);

    // 4) autopoietic transform (LUT-based, atomic-free, fp16 I/O)
    transform_kernel<<<dim3(BATCH * SEQ), dim3(256), 0, stream>>>(
        scoresH, lutbuf, t0H, partials);

    // 5) fused coef + residual/softmax + attn@v (64-row, one-shot vT, no K barriers)
    softmax_attnv<<<dim3(8, 32), dim3(256), 0, stream>>>(
        scoresH, t0H, partials, vT, otmp);

    // 6) out = out_tmp @ wo^T + bo (32x64 tiles, 512 blocks)
    gemm_proj<<<dim3(8, 64), dim3(256), 0, stream>>>(otmp, woh, bo, out);
}

// Round 10
// 150.442 us; speedup vs baseline: 1.1275x; 1.1275x over previous
//
#include <hip/hip_runtime.h>
#include <math.h>

// Problem constants (reference: B=4, S=512, E=512, H=8, DH=64, HID=128)
#define BATCH 4
#define SEQ   512
#define EMB   512
#define NH    8
#define DHD   64
#define HIDN  128
#define ALPHA 0.1f
#define EPSS  0.05f

// LUT for the pointwise conv-chain -> sigmoid function of `scaled`
#define LUTN  2048
#define XMIN  (-0.4f)
#define XSTEP (0.8f / LUTN)

typedef __attribute__((ext_vector_type(8))) short  bf16x8;
typedef __attribute__((ext_vector_type(4))) short  s16x4;
typedef __attribute__((ext_vector_type(4))) float  f32x4;
#define MFMA(a,b,c) __builtin_amdgcn_mfma_f32_16x16x32_bf16((a),(b),(c),0,0,0)

__device__ __forceinline__ unsigned short f2bf(float f) {
    union { float f; unsigned u; } v; v.f = f;
    unsigned r = v.u + 0x7fffu + ((v.u >> 16) & 1u);   // RNE; inputs finite
    return (unsigned short)(r >> 16);
}
__device__ __forceinline__ float bf2f(unsigned short h) {
    union { unsigned u; float f; } v; v.u = ((unsigned)h) << 16;
    return v.f;
}
__device__ __forceinline__ float f16tof(unsigned short h) {
    union { unsigned short s; _Float16 f; } v; v.s = h; return (float)v.f;
}
__device__ __forceinline__ unsigned short ftof16(float f) {
    union { unsigned short s; _Float16 f; } v; v.f = (_Float16)f; return v.s;
}

// async global->LDS, 16B per lane; LDS dst = uniform base + lane*16
__device__ __forceinline__ void async_lds16(const unsigned short* g, unsigned short* l) {
    __builtin_amdgcn_global_load_lds(
        (const __attribute__((address_space(1))) void*)g,
        (__attribute__((address_space(3))) void*)l, 16, 0, 0);
}

// ---------------- BK=64 GEMM core (64/32-row blocks) ---------------------
// NT: C[m,n] = sum_k A[m,k]*B[n,k], row-major bf16, K = KS*64.
// 256 thr / 4 waves as 2x2. Per K-step: stage via global_load_lds (XOR
// chunk swizzle, full 32-bank rows), 1 drain barrier, MFMAs, 1 barrier.
template<int KS, int UN, int MT>
__device__ __forceinline__ void gemm_core64(
    const unsigned short* __restrict__ A, const unsigned short* __restrict__ B,
    int m0, int n0, unsigned short* sA, unsigned short* sB, f32x4 (&acc)[2][4])
{
    const int K = KS * 64;
    const int tid = threadIdx.x, w = tid >> 6, lane = tid & 63;
    const int quad = lane >> 4, r = lane & 15;
    const int wm = w >> 1, wn = w & 1;
    const int lrow = lane >> 3, lc = lane & 7;
    const int sc = lc ^ lrow;                     // swizzled global chunk
    constexpr int AF = MT / 32;                   // A frags per wave
    constexpr int NB = UN;                        // B staging calls per wave

    const unsigned short* ag[2]; unsigned short* dAu[2];
    #pragma unroll
    for (int c = 0; c < AF; c++) {
        const int rb = w * (8 * AF) + c * 8;
        ag[c]  = A + (long)(m0 + rb + lrow) * K + sc * 8;
        dAu[c] = sA + rb * 64;
    }
    const unsigned short* bg[4]; unsigned short* dBu[4];
    #pragma unroll
    for (int c = 0; c < NB; c++) {
        const int rb = w * (8 * NB) + c * 8;
        bg[c]  = B + (long)(n0 + rb + lrow) * K + sc * 8;
        dBu[c] = sB + rb * 64;
    }

    for (int s = 0; s < KS; s++) {
        const int k0 = s * 64;
        #pragma unroll
        for (int c = 0; c < AF; c++) async_lds16(ag[c] + k0, dAu[c]);
        #pragma unroll
        for (int c = 0; c < NB; c++) async_lds16(bg[c] + k0, dBu[c]);
        __syncthreads();
        #pragma unroll
        for (int kc = 0; kc < 2; kc++) {
            bf16x8 af[2], bfr[4];
            #pragma unroll
            for (int t = 0; t < AF; t++) {
                const int row = wm * (16 * AF) + t * 16 + r;
                af[t] = *(const bf16x8*)(sA + row * 64 + ((kc * 4 + quad) ^ (row & 7)) * 8);
            }
            #pragma unroll
            for (int u = 0; u < UN; u++) {
                const int row = wn * (16 * UN) + u * 16 + r;
                bfr[u] = *(const bf16x8*)(sB + row * 64 + ((kc * 4 + quad) ^ (row & 7)) * 8);
            }
            #pragma unroll
            for (int t = 0; t < AF; t++)
                #pragma unroll
                for (int u = 0; u < UN; u++)
                    acc[t][u] = MFMA(af[t], bfr[u], acc[t][u]);
        }
        __syncthreads();
    }
}

// ---------------- fused QKV projection -----------------------------------
// A = x_ext [2048,1536]=[xh|xl|xh]; B = w_ext [1536,1536]=[wh|wh|wl]
// -> exact 3-term compensated product. 64x64 tiles, grid (24,32) = 768
// blocks = 3 blocks/CU (25 KB LDS): proven r8 sweet spot.
__global__ __launch_bounds__(256) void gemm_qkv(
    const unsigned short* __restrict__ x_ext, const unsigned short* __restrict__ w_ext,
    const float* __restrict__ bq, const float* __restrict__ bk, const float* __restrict__ bv,
    unsigned short* __restrict__ q_ext, unsigned short* __restrict__ k_ext,
    unsigned short* __restrict__ vT)
{
    __shared__ __align__(16) unsigned short sA[64 * 64];
    __shared__ __align__(16) unsigned short sB[64 * 64];
    __shared__ float sC[64 * 68];

    const int m0 = blockIdx.y * 64, n0 = blockIdx.x * 64;
    f32x4 acc[2][4] = {};
    gemm_core64<24, 2, 64>(x_ext, w_ext, m0, n0, sA, sB, acc);

    const int tid = threadIdx.x, w = tid >> 6, lane = tid & 63;
    const int quad = lane >> 4, r = lane & 15;
    const int wm = w >> 1, wn = w & 1;
    #pragma unroll
    for (int t = 0; t < 2; t++)
        #pragma unroll
        for (int u = 0; u < 2; u++)
            #pragma unroll
            for (int g = 0; g < 4; g++)
                sC[(wm * 32 + t * 16 + quad * 4 + g) * 68 + wn * 32 + u * 16 + r] = acc[t][u][g];
    __syncthreads();

    const int which = n0 >> 9;       // 0:q 1:k 2:v
    const int n0l = n0 & 511;        // = h0*64
    const int h0 = n0l >> 6;
    const int b = m0 >> 9, s0 = m0 & 511;

    if (which < 2) {
        const float scl = (which == 0) ? 0.125f : 1.0f;
        const float* bias = (which == 0) ? bq : bk;
        unsigned* dst = (unsigned*)((which == 0) ? q_ext : k_ext);
        #pragma unroll
        for (int seg = 0; seg < 3; seg++) {
            // q_ext row = [hi | lo | hi]; k_ext row = [hi | hi | lo]
            const bool lo = (which == 0) ? (seg == 1) : (seg == 2);
            #pragma unroll
            for (int it = 0; it < 8; it++) {
                const int idx = it * 256 + tid;        // 0..2047
                const int sl = idx >> 5;               // s-row 0..63
                const int jc = idx & 31;               // d pair
                const int nc = jc * 2;
                float v0 = (sC[sl * 68 + nc]     + bias[n0l + nc])     * scl;
                float v1 = (sC[sl * 68 + nc + 1] + bias[n0l + nc + 1]) * scl;
                unsigned short a0 = f2bf(v0), a1 = f2bf(v1);
                if (lo) { a0 = f2bf(v0 - bf2f(a0)); a1 = f2bf(v1 - bf2f(a1)); }
                const long orow = (long)(b * NH + h0) * SEQ + s0 + sl;
                dst[orow * 96 + seg * 32 + jc] = (unsigned)a0 | ((unsigned)a1 << 16);
            }
        }
    } else {
        unsigned* dst = (unsigned*)vT;
        #pragma unroll
        for (int it = 0; it < 8; it++) {
            const int idx = it * 256 + tid;
            const int d = idx >> 5;                    // 0..63
            const int jc = idx & 31;                   // s pair
            const int sl = jc * 2;
            const float bvv = bv[n0l + d];
            const float v0 = sC[sl * 68 + d] + bvv;
            const float v1 = sC[(sl + 1) * 68 + d] + bvv;
            const long orow = (long)(b * NH + h0) * DHD + d;
            dst[orow * 256 + (s0 >> 1) + jc] = (unsigned)f2bf(v0) | ((unsigned)f2bf(v1) << 16);
        }
    }
}

// ---------------- scores = q_ext @ k_ext^T per (b,h), K=192 -> fp16 ------
__global__ __launch_bounds__(256) void gemm_scores(
    const unsigned short* __restrict__ q_ext, const unsigned short* __restrict__ k_ext,
    unsigned short* __restrict__ scoresH)
{
    __shared__ __align__(16) unsigned short sA[64 * 64];
    __shared__ __align__(16) unsigned short sB[128 * 64];
    const int z = blockIdx.z;
    const int m0 = blockIdx.y * 64, n0 = blockIdx.x * 128;
    f32x4 acc[2][4] = {};
    gemm_core64<3, 4, 64>(q_ext + (long)z * SEQ * 192, k_ext + (long)z * SEQ * 192,
                          m0, n0, sA, sB, acc);

    const int tid = threadIdx.x, w = tid >> 6, lane = tid & 63;
    const int quad = lane >> 4, r = lane & 15;
    const int wm = w >> 1, wn = w & 1;
    unsigned short* hC = sB;   // reuse as 64x128 fp16 tile
    #pragma unroll
    for (int t = 0; t < 2; t++)
        #pragma unroll
        for (int u = 0; u < 4; u++)
            #pragma unroll
            for (int g = 0; g < 4; g++) {
                const int ml = wm * 32 + t * 16 + quad * 4 + g;
                const int nl = wn * 64 + u * 16 + r;
                hC[ml * 128 + nl] = ftof16(fminf(fmaxf(acc[t][u][g], -15.f), 15.f));
            }
    __syncthreads();
    #pragma unroll
    for (int it = 0; it < 4; it++) {
        const int id = it * 256 + tid;
        const int ml = id >> 4, ch = id & 15;
        *(uint4*)(scoresH + ((long)z * SEQ + m0 + ml) * SEQ + n0 + ch * 8) =
            *(const uint4*)(hC + ml * 128 + ch * 8);
    }
}

// ---------------- out = out_tmp @ wo^T + bo (32x64 tiles) ----------------
__global__ __launch_bounds__(256) void gemm_proj(
    const unsigned short* __restrict__ otmp, const unsigned short* __restrict__ woh,
    const float* __restrict__ bo, float* __restrict__ out)
{
    __shared__ __align__(16) unsigned short sA[32 * 64];
    __shared__ __align__(16) unsigned short sB[64 * 64];
    const int m0 = blockIdx.y * 32, n0 = blockIdx.x * 64;
    f32x4 acc[2][4] = {};
    gemm_core64<8, 2, 32>(otmp, woh, m0, n0, sA, sB, acc);
    const int tid = threadIdx.x, w = tid >> 6, lane = tid & 63;
    const int quad = lane >> 4, r = lane & 15;
    const int wm = w >> 1, wn = w & 1;
    #pragma unroll
    for (int u = 0; u < 2; u++)
        #pragma unroll
        for (int g = 0; g < 4; g++) {
            const int m = m0 + wm * 16 + quad * 4 + g;
            const int n = n0 + wn * 32 + u * 16 + r;
            out[(long)m * EMB + n] = acc[0][u][g] + bo[n];
        }
}

// ---------------- block reduction helpers (blockDim=256, 4 waves) --------
__device__ __forceinline__ float blockReduceSum(float v, float* sred) {
    #pragma unroll
    for (int o = 32; o > 0; o >>= 1) v += __shfl_down(v, o);
    __syncthreads();
    if ((threadIdx.x & 63) == 0) sred[threadIdx.x >> 6] = v;
    __syncthreads();
    return (sred[0] + sred[1]) + (sred[2] + sred[3]);
}
__device__ __forceinline__ float blockReduceMax(float v, float* sred) {
    #pragma unroll
    for (int o = 32; o > 0; o >>= 1) v = fmaxf(v, __shfl_down(v, o));
    __syncthreads();
    if ((threadIdx.x & 63) == 0) sred[threadIdx.x >> 6] = v;
    __syncthreads();
    return fmaxf(fmaxf(sred[0], sred[1]), fmaxf(sred[2], sred[3]));
}

// ---------------- fused prep: LUT + ext-K split builds (vectorized) ------
// blocks [0,9): LUT; blocks [9, 9+2048): 4 elems/thread via float4.
__global__ __launch_bounds__(256) void prep_kernel(
    const float* __restrict__ x,
    const float* __restrict__ wq, const float* __restrict__ wk,
    const float* __restrict__ wv, const float* __restrict__ wo,
    const float* __restrict__ w1, const float* __restrict__ b1,
    const float* __restrict__ w2, const float* __restrict__ b2,
    unsigned short* __restrict__ x_ext, unsigned short* __restrict__ w_ext,
    unsigned short* __restrict__ woh, float* __restrict__ lut)
{
    const int blk = blockIdx.x;
    if (blk < 9) {
        const int i = blk * 256 + threadIdx.x;
        if (i > LUTN) return;
        const float xv = XMIN + i * XSTEP;
        float a = 0.f;
        for (int h = 0; h < HIDN; h++) {
            float hv = xv * w1[h] + b1[h];
            hv = fminf(fmaxf(hv, -5.f), 5.f);
            hv = fmaxf(hv, 0.f);
            a += hv * w2[h];
        }
        a += b2[0];
        a = fminf(fmaxf(a, -5.f), 5.f);
        const float taylor = fminf(fmaxf(1.f + 2.5f * a, 0.5f), 1.5f);
        lut[i] = 1.f / (1.f + expf(-taylor));
        return;
    }
    const int e = ((blk - 9) * 256 + threadIdx.x) * 4;   // 0 .. 2097148
    float4 v;
    s16x4 h, l;
    if (e < 1048576) {
        v = *(const float4*)(x + e);
        const float vv[4] = { v.x, v.y, v.z, v.w };
        #pragma unroll
        for (int u = 0; u < 4; u++) {
            h[u] = (short)f2bf(vv[u]);
            l[u] = (short)f2bf(vv[u] - bf2f((unsigned short)h[u]));
        }
        const int m = e >> 9, k = e & 511;
        const long bb = (long)m * 1536 + k;
        *(s16x4*)(x_ext + bb)        = h;        // [xh|xl|xh]
        *(s16x4*)(x_ext + bb + 512)  = l;
        *(s16x4*)(x_ext + bb + 1024) = h;
    } else if (e < 1835008) {
        const int j = e - 1048576;
        const float* src = (j < 262144) ? (wq + j)
                          : (j < 524288 ? (wk + (j - 262144)) : (wv + (j - 524288)));
        v = *(const float4*)src;
        const float vv[4] = { v.x, v.y, v.z, v.w };
        #pragma unroll
        for (int u = 0; u < 4; u++) {
            h[u] = (short)f2bf(vv[u]);
            l[u] = (short)f2bf(vv[u] - bf2f((unsigned short)h[u]));
        }
        const int n = j >> 9, k = j & 511;
        const long bb = (long)n * 1536 + k;
        *(s16x4*)(w_ext + bb)        = h;        // [wh|wh|wl]
        *(s16x4*)(w_ext + bb + 512)  = h;
        *(s16x4*)(w_ext + bb + 1024) = l;
    } else {
        const int j = e - 1835008;
        v = *(const float4*)(wo + j);
        h[0] = (short)f2bf(v.x); h[1] = (short)f2bf(v.y);
        h[2] = (short)f2bf(v.z); h[3] = (short)f2bf(v.w);
        *(s16x4*)(woh + j) = h;
    }
}

// ---------------- transform kernel: one block per (b,i) row --------------
__global__ __launch_bounds__(256) void transform_kernel(
    const unsigned short* __restrict__ scoresH, // [B,H,S,S] fp16 (clamped)
    const float* __restrict__ lut,              // [LUTN+1]
    unsigned short* __restrict__ t0H,           // [B,S,S] fp16
    float4* __restrict__ partials)              // [B*S] float4 slots
{
    const int rr = blockIdx.x;
    const int b = rr >> 9, i = rr & 511;
    const int tid = threadIdx.x;

    __shared__ float slut[LUTN + 1];
    __shared__ float sred[4];

    for (int u = tid; u <= LUTN; u += 256) slut[u] = lut[u];

    const unsigned* baseU =
        (const unsigned*)(scoresH + (((long)(b * NH)) * SEQ + i) * SEQ) + tid;
    float s0 = 0.f, s1 = 0.f;
    #pragma unroll
    for (int h = 0; h < NH; h++) {
        const unsigned pv = baseU[h * (SEQ * SEQ / 2)];
        s0 += f16tof((unsigned short)pv);
        s1 += f16tof((unsigned short)(pv >> 16));
    }
    float mv[2] = { s0 * 0.125f, s1 * 0.125f };
    __syncthreads();

    float sigv[2], mclip[2];
    float lmax = -1e30f;
    #pragma unroll
    for (int u = 0; u < 2; u++) {
        const float m = mv[u];
        const float x = fminf(fmaxf(m, -8.f), 8.f) * EPSS;
        float t = (x - XMIN) * (1.0f / XSTEP);
        int idx = (int)t;
        idx = idx < 0 ? 0 : (idx > LUTN - 1 ? LUTN - 1 : idx);
        const float frac = t - (float)idx;
        const float l0 = slut[idx], l1 = slut[idx + 1];
        sigv[u] = l0 + frac * (l1 - l0);
        const float mc = fminf(fmaxf(m, -10.f), 10.f);
        mclip[u] = mc;
        lmax = fmaxf(lmax, mc);
    }

    const float rmax = blockReduceMax(lmax, sred);
    float ex[2], lsum = 0.f;
    #pragma unroll
    for (int u = 0; u < 2; u++) { ex[u] = expf(mclip[u] - rmax); lsum += ex[u]; }
    const float rsum = blockReduceSum(lsum, sred);
    const float inv = 1.f / rsum;

    float hent[2], lmax2 = -1e30f;
    #pragma unroll
    for (int u = 0; u < 2; u++) {
        const float p = ex[u] * inv;
        const float he = -p * logf(p + 1e-6f);
        hent[u] = 3.f * he;
        lmax2 = fmaxf(lmax2, hent[u]);
    }
    const float rmax2 = blockReduceMax(lmax2, sred);
    float ex2[2], lsum2 = 0.f;
    #pragma unroll
    for (int u = 0; u < 2; u++) { ex2[u] = expf(hent[u] - rmax2); lsum2 += ex2[u]; }
    const float rsum2 = blockReduceSum(lsum2, sred);
    const float inv2 = 1.f / rsum2;

    float tv[2];
    #pragma unroll
    for (int u = 0; u < 2; u++) tv[u] = sigv[u] * (ex2[u] * inv2);
    ((unsigned*)t0H)[((long)b * SEQ + i) * (SEQ / 2) + tid] =
        (unsigned)ftof16(tv[0]) | ((unsigned)ftof16(tv[1]) << 16);

    float s_m  = blockReduceSum(mv[0] + mv[1], sred);
    float s_m2 = blockReduceSum(mv[0] * mv[0] + mv[1] * mv[1], sred);
    float s_t  = blockReduceSum(tv[0] + tv[1], sred);
    float s_t2 = blockReduceSum(tv[0] * tv[0] + tv[1] * tv[1], sred);
    if (tid == 0) partials[rr] = make_float4(s_m, s_m2, s_t, s_t2);
}

// ---------------- fused coef + softmax + attn@v --------------------------
// Grid (16 m-tiles of 32 rows, 32 z=(b,h)).
__global__ __launch_bounds__(256) void softmax_attnv(
    const unsigned short* __restrict__ scoresH, // [B,H,S,S] fp16
    const unsigned short* __restrict__ t0H,     // [B,S,S] fp16
    const float4* __restrict__ partials,        // [B*S]
    const unsigned short* __restrict__ vT,      // [B,H,DH,S] bf16
    unsigned short* __restrict__ otmp)          // [B*S, E] bf16
{
    __shared__ __align__(16) unsigned short attnS[32 * 520];  // bf16, +8 pad
    __shared__ __align__(16) unsigned short sB[64 * 64];
    __shared__ float sC[32 * 66];
    __shared__ float sred[4];

    const int m0 = blockIdx.x * 32;
    const int z  = blockIdx.y;
    const int b  = z >> 3, h = z & 7;
    const int tid = threadIdx.x, wv = tid >> 6, lane = tid & 63;

    // --- phase A: coef (redundant per block) ---
    const float4 p0 = partials[b * SEQ + tid];
    const float4 p1 = partials[b * SEQ + tid + 256];
    float sm  = blockReduceSum(p0.x + p1.x, sred);
    float sm2 = blockReduceSum(p0.y + p1.y, sred);
    float st  = blockReduceSum(p0.z + p1.z, sred);
    float st2 = blockReduceSum(p0.w + p1.w, sred);
    const float n = (float)SEQ * (float)SEQ;
    const float gamma = fminf(fmaxf((sqrtf(sm2) + 1e-4f) / (sqrtf(st2) + 1e-4f), 0.8f), 1.2f);
    const float o_mean = sm / n, t0m = st / n;
    const float o_std = sqrtf(fmaxf(fmaxf(sm2 / n - o_mean * o_mean, 0.f), 0.01f));
    const float t_std = sqrtf(fmaxf(gamma * gamma * fmaxf(st2 / n - t0m * t0m, 0.f), 0.01f));
    const float gdyn = fminf(fmaxf(o_std / t_std, 0.8f), 1.2f);
    const float c1 = gdyn * gamma;
    const float c0 = o_mean - c1 * t0m;

    // --- phase B: softmax 32 rows -> LDS bf16 tile ---
    const int j0 = lane * 8;
    for (int it = 0; it < 8; it++) {
        const int rowl = it * 4 + wv;
        const bf16x8 sr = *(const bf16x8*)(scoresH + ((long)z * SEQ + m0 + rowl) * SEQ + j0);
        const bf16x8 tr = *(const bf16x8*)(t0H + ((long)b * SEQ + m0 + rowl) * SEQ + j0);
        float sv[8];
        float lmax = -1e30f;
        #pragma unroll
        for (int u = 0; u < 8; u++) {
            float s = f16tof((unsigned short)sr[u])
                    + ALPHA * (c0 + c1 * f16tof((unsigned short)tr[u]));
            s = fminf(fmaxf(s, -15.f), 15.f);
            sv[u] = s;
            lmax = fmaxf(lmax, s);
        }
        #pragma unroll
        for (int o = 32; o > 0; o >>= 1) lmax = fmaxf(lmax, __shfl_down(lmax, o));
        lmax = __shfl(lmax, 0);
        float lsum = 0.f;
        #pragma unroll
        for (int u = 0; u < 8; u++) { sv[u] = expf(sv[u] - lmax); lsum += sv[u]; }
        #pragma unroll
        for (int o = 32; o > 0; o >>= 1) lsum += __shfl_down(lsum, o);
        lsum = __shfl(lsum, 0);
        const float inv = 1.f / lsum;
        bf16x8 pk;
        #pragma unroll
        for (int u = 0; u < 8; u++) pk[u] = (short)f2bf(sv[u] * inv);
        *(bf16x8*)(attnS + rowl * 520 + j0) = pk;
    }
    __syncthreads();

    // --- phase C: attn(LDS) @ vT(staged, BK=64) ---
    const int quad = lane >> 4, r = lane & 15;
    const int wm = wv >> 1, wn = wv & 1;
    const int lrow = lane >> 3, lc = lane & 7;
    const int sc = lc ^ lrow;
    const unsigned short* bg0 = vT + (long)z * DHD * SEQ + (long)(wv * 16 + lrow) * SEQ + sc * 8;
    const unsigned short* bg1 = bg0 + 8 * SEQ;
    unsigned short* dB0 = sB + (wv * 16) * 64;
    unsigned short* dB1 = sB + (wv * 16 + 8) * 64;
    f32x4 acc[2] = {};
    for (int s = 0; s < 8; s++) {
        const int k0 = s * 64;
        async_lds16(bg0 + k0, dB0);
        async_lds16(bg1 + k0, dB1);
        __syncthreads();
        #pragma unroll
        for (int kc = 0; kc < 2; kc++) {
            const bf16x8 a = *(const bf16x8*)(attnS + (wm * 16 + r) * 520 + k0 + kc * 32 + quad * 8);
            #pragma unroll
            for (int u = 0; u < 2; u++) {
                const int row = wn * 32 + u * 16 + r;
                const bf16x8 bb = *(const bf16x8*)(sB + row * 64 + ((kc * 4 + quad) ^ (row & 7)) * 8);
                acc[u] = MFMA(a, bb, acc[u]);
            }
        }
        __syncthreads();
    }

    // --- phase D: epilogue ---
    #pragma unroll
    for (int u = 0; u < 2; u++)
        #pragma unroll
        for (int g = 0; g < 4; g++)
            sC[(wm * 16 + quad * 4 + g) * 66 + wn * 32 + u * 16 + r] = acc[u][g];
    __syncthreads();
    unsigned* dst = (unsigned*)otmp;
    #pragma unroll
    for (int it = 0; it < 4; it++) {
        const int idx = it * 256 + tid;
        const int sr2 = idx >> 5, jc = idx & 31;
        const float v0 = sC[sr2 * 66 + jc * 2], v1 = sC[sr2 * 66 + jc * 2 + 1];
        dst[((long)(b * SEQ + m0 + sr2)) * 256 + h * 32 + jc] =
            (unsigned)f2bf(v0) | ((unsigned)f2bf(v1) << 16);
    }
}

// -------------------------------------------------------------------------
extern "C" void kernel_launch(void* const* d_in, const int* in_sizes, int n_in,
                              void* d_out, int out_size, void* d_ws, size_t ws_size,
                              hipStream_t stream) {
    const float* x  = (const float*)d_in[0];
    const float* wq = (const float*)d_in[1];
    const float* bq = (const float*)d_in[2];
    const float* wk = (const float*)d_in[3];
    const float* bk = (const float*)d_in[4];
    const float* wv = (const float*)d_in[5];
    const float* bv = (const float*)d_in[6];
    const float* wo = (const float*)d_in[7];
    const float* bo = (const float*)d_in[8];
    const float* w1 = (const float*)d_in[9];
    const float* b1 = (const float*)d_in[10];
    const float* w2 = (const float*)d_in[11];
    const float* b2 = (const float*)d_in[12];
    float* out = (float*)d_out;

    // ---- workspace layout (~48 MB) ----
    char* wsb = (char*)d_ws;
    unsigned short* scoresH = (unsigned short*)wsb;        // 16 MB [B,H,S,S] fp16
    unsigned short* t0H     = scoresH + 8388608;           // 2 MB  [B,S,S] fp16
    float4* partials = (float4*)(t0H + 1048576);           // 32 KB
    float*  lutbuf   = (float*)(partials + 2048);
    unsigned short* u16 = (unsigned short*)(wsb + (20u << 20));
    unsigned short* x_ext = u16;                           // 6 MB   [2048,1536]
    unsigned short* w_ext = x_ext + 3145728;               // 4.5 MB [1536,1536]
    unsigned short* q_ext = w_ext + 2359296;               // 6 MB   [B*H*S,192]
    unsigned short* k_ext = q_ext + 3145728;               // 6 MB
    unsigned short* vT    = k_ext + 3145728;               // 2 MB   [B,H,DH,S]
    unsigned short* otmp  = vT + 1048576;                  // 2 MB   [B*S, E]
    unsigned short* woh   = otmp + 1048576;                // 0.5 MB [E,E]

    // 1) prep: LUT + ext-K split builds (vectorized, 4 elems/thread)
    prep_kernel<<<dim3(9 + 2048), dim3(256), 0, stream>>>(
        x, wq, wk, wv, wo, w1, b1, w2, b2, x_ext, w_ext, woh, lutbuf);

    // 2) fused QKV projection (compensated bf16, K=1536, BK=64, 64x64)
    gemm_qkv<<<dim3(24, 32), dim3(256), 0, stream>>>(
        x_ext, w_ext, bq, bk, bv, q_ext, k_ext, vT);

    // 3) scores = q @ k^T per (b,h) (compensated, K=192) -> fp16, clamp
    gemm_scores<<<dim3(4, 8, 32), dim3(256), 0, stream>>>(q_ext, k_ext, scoresH);

    // 4) autopoietic transform (LUT-based, atomic-free, fp16 I/O)
    transform_kernel<<<dim3(BATCH * SEQ), dim3(256), 0, stream>>>(
        scoresH, lutbuf, t0H, partials);

    // 5) fused coef + residual/softmax + attn@v (fp16 in, BK=64)
    softmax_attnv<<<dim3(16, 32), dim3(256), 0, stream>>>(
        scoresH, t0H, partials, vT, otmp);

    // 6) out = out_tmp @ wo^T + bo (32x64 tiles, 512 blocks)
    gemm_proj<<<dim3(8, 64), dim3(256), 0, stream>>>(otmp, woh, bo, out);
}